// Round 1
// baseline (338.854 us; speedup 1.0000x reference)
//
#include <hip/hip_runtime.h>

#define T_LEN 1024
#define S_LEN 512
#define B_LEN 64

// Scaled HMM forward pass, one block per batch element, one wave per block.
// States: lane owns s = 8*lane + i, i in 0..7, carried in registers.
// Transition A = 0.9*I + (eps/S)*J  =>  alpha' = E o (0.9*alpha + (eps/S)*Z).
__global__ __launch_bounds__(64) void hmm_fwd_kernel(const float* __restrict__ obvs,
                                                     const float* __restrict__ mu,
                                                     const float* __restrict__ ln_pi,
                                                     float* __restrict__ out)
{
    const int b = blockIdx.x;
    const int lane = threadIdx.x;

    __shared__ float s_obs[T_LEN];
    const float* orow = obvs + b * T_LEN;
#pragma unroll
    for (int k = 0; k < T_LEN / 64; ++k)
        s_obs[lane + 64 * k] = orow[lane + 64 * k];
    __syncthreads();

    const float4 mu_a = reinterpret_cast<const float4*>(mu)[2 * lane];
    const float4 mu_b = reinterpret_cast<const float4*>(mu)[2 * lane + 1];
    const float4 pi_a = reinterpret_cast<const float4*>(ln_pi)[2 * lane];
    const float4 pi_b = reinterpret_cast<const float4*>(ln_pi)[2 * lane + 1];
    const float m[8]  = {mu_a.x, mu_a.y, mu_a.z, mu_a.w, mu_b.x, mu_b.y, mu_b.z, mu_b.w};
    const float lp[8] = {pi_a.x, pi_a.y, pi_a.z, pi_a.w, pi_b.x, pi_b.y, pi_b.z, pi_b.w};

    const float C1 = -0.7213475204444817f;   // -0.5 * log2(e)
    const float C2 = -1.3257480647361593f;   // -0.5 * log2(2*pi)
    const float LOG2E = 1.4426950408889634f;
    const float C9 = 0.9f;                   // 1 - eps
    const float KE = 0.1f / 512.0f;          // eps / S
    const float LN2 = 0.6931471805599453f;

    // t = 0: alpha_0 = exp(ln_pi + ln_e0), all in exp2 domain
    float a[8];
    {
        const float o0 = s_obs[0];
#pragma unroll
        for (int i = 0; i < 8; ++i) {
            const float d = o0 - m[i];
            const float q = fmaf(d * d, C1, C2);
            a[i] = __builtin_amdgcn_exp2f(fmaf(lp[i], LOG2E, q));
        }
    }
    float loc = ((a[0] + a[1]) + (a[2] + a[3])) + ((a[4] + a[5]) + (a[6] + a[7]));
#pragma unroll
    for (int mask = 1; mask < 64; mask <<= 1)
        loc += __shfl_xor(loc, mask, 64);
    float Z = loc;          // lane-uniform sum of alpha
    float acc2 = 0.0f;      // accumulated log2 of normalization factors

    for (int t = 1; t < T_LEN; ++t) {
        const float o = s_obs[t];
        const float kz = KE * Z;
        float e[8];
#pragma unroll
        for (int i = 0; i < 8; ++i) {
            const float d = o - m[i];
            e[i] = __builtin_amdgcn_exp2f(fmaf(d * d, C1, C2));
        }
#pragma unroll
        for (int i = 0; i < 8; ++i)
            a[i] = e[i] * fmaf(a[i], C9, kz);
        float l = ((a[0] + a[1]) + (a[2] + a[3])) + ((a[4] + a[5]) + (a[6] + a[7]));
#pragma unroll
        for (int mask = 1; mask < 64; mask <<= 1)
            l += __shfl_xor(l, mask, 64);
        Z = l;
        if ((t & 7) == 7) {          // renormalize every 8 steps (keeps f32 in range)
            acc2 += __builtin_amdgcn_logf(Z);            // log2
            const float r = __builtin_amdgcn_rcpf(Z);
#pragma unroll
            for (int i = 0; i < 8; ++i) a[i] *= r;
            Z = 1.0f;
        }
    }

    if (lane == 0) {
        const float res = LN2 * (acc2 + __builtin_amdgcn_logf(Z));
        atomicAdd(out, res);
    }
}

extern "C" void kernel_launch(void* const* d_in, const int* in_sizes, int n_in,
                              void* d_out, int out_size, void* d_ws, size_t ws_size,
                              hipStream_t stream)
{
    const float* obvs  = (const float*)d_in[0];
    const float* mu    = (const float*)d_in[1];
    const float* ln_pi = (const float*)d_in[2];
    float* out = (float*)d_out;

    hipMemsetAsync(out, 0, sizeof(float), stream);
    hmm_fwd_kernel<<<B_LEN, 64, 0, stream>>>(obvs, mu, ln_pi, out);
}

// Round 3
// 148.208 us; speedup vs baseline: 2.2863x; 2.2863x over previous
//
#include <hip/hip_runtime.h>

#define T_LEN 1024
#define B_LEN 64

// One DPP-add level: x += dpp_move(x, CTRL), out-of-bounds lanes read 0.
// CTRL must be a compile-time constant (hardware immediate).
template <int CTRL>
__device__ __forceinline__ float dpp_add(float x)
{
    int y = __builtin_amdgcn_update_dpp(0, __builtin_bit_cast(int, x), CTRL, 0xf, 0xf, true);
    return x + __builtin_bit_cast(float, y);
}

// Wave64 sum via DPP prefix (row_shr 1/2/4/8 + row_bcast 15/31); total lands in
// lane 63; broadcast to all lanes through an SGPR with readlane.
__device__ __forceinline__ float wave_sum_bcast(float x)
{
    x = dpp_add<0x111>(x);  // row_shr:1
    x = dpp_add<0x112>(x);  // row_shr:2
    x = dpp_add<0x114>(x);  // row_shr:4
    x = dpp_add<0x118>(x);  // row_shr:8
    x = dpp_add<0x142>(x);  // row_bcast:15
    x = dpp_add<0x143>(x);  // row_bcast:31
    int z = __builtin_amdgcn_readlane(__builtin_bit_cast(int, x), 63);
    return __builtin_bit_cast(float, z);
}

// Scaled HMM forward pass; one block = one batch row = one wave.
// Lane owns states s = 8*lane + i. alpha' = E o (0.9*alpha + (eps/S)*Z).
// Renormalize every 8 steps; the 1/Z scale is folded into the NEXT step's
// coefficients (c9 = 0.9*r, kz = KE) so rcp latency sits off the Z chain.
__global__ __launch_bounds__(64) void hmm_fwd_kernel(const float* __restrict__ obvs,
                                                     const float* __restrict__ mu,
                                                     const float* __restrict__ ln_pi,
                                                     float* __restrict__ out)
{
    const int b = blockIdx.x;
    const int lane = threadIdx.x;

    __shared__ float s_obs[T_LEN + 8];
    const float* orow = obvs + (size_t)b * T_LEN;
#pragma unroll
    for (int k = 0; k < T_LEN / 64; ++k)
        s_obs[lane + 64 * k] = orow[lane + 64 * k];
    if (lane < 8) s_obs[T_LEN + lane] = 0.0f;   // pad for the t+1 prefetch at t=1023
    __syncthreads();

    const float4 mua = reinterpret_cast<const float4*>(mu)[2 * lane];
    const float4 mub = reinterpret_cast<const float4*>(mu)[2 * lane + 1];
    const float4 pia = reinterpret_cast<const float4*>(ln_pi)[2 * lane];
    const float4 pib = reinterpret_cast<const float4*>(ln_pi)[2 * lane + 1];
    const float m[8]  = {mua.x, mua.y, mua.z, mua.w, mub.x, mub.y, mub.z, mub.w};
    const float lp[8] = {pia.x, pia.y, pia.z, pia.w, pib.x, pib.y, pib.z, pib.w};

    const float C1    = -0.7213475204444817f;   // -0.5 * log2(e)
    const float C2    = -1.3257480647361593f;   // -0.5 * log2(2*pi)
    const float LOG2E =  1.4426950408889634f;
    const float KE    =  0.1f / 512.0f;         // eps / S
    const float LN2   =  0.6931471805599453f;

    float a[8], e[8];
    float Z, c9, kz;
    float acc2 = 0.0f;                          // accumulated log2 of scale factors

    {   // t = 0: alpha_0 = exp(ln_pi + ln_e0)
        const float o = s_obs[0];
#pragma unroll
        for (int i = 0; i < 8; ++i) {
            const float d = o - m[i];
            a[i] = __builtin_amdgcn_exp2f(fmaf(lp[i], LOG2E, fmaf(d * d, C1, C2)));
        }
        float l = ((a[0] + a[1]) + (a[2] + a[3])) + ((a[4] + a[5]) + (a[6] + a[7]));
        Z  = wave_sum_bcast(l);
        c9 = 0.9f;
        kz = KE * Z;
    }
    {   // preload emissions for t = 1
        const float o = s_obs[1];
#pragma unroll
        for (int i = 0; i < 8; ++i) {
            const float d = o - m[i];
            e[i] = __builtin_amdgcn_exp2f(fmaf(d * d, C1, C2));
        }
    }

    auto step = [&](int t, bool renorm) {
        // consume current emissions (the only state-dependent chain)
#pragma unroll
        for (int i = 0; i < 8; ++i)
            a[i] = e[i] * fmaf(a[i], c9, kz);
        // prefetch next step's emissions (state-independent; fills DPP stalls)
        const float on = s_obs[t + 1];
        float en[8];
#pragma unroll
        for (int i = 0; i < 8; ++i) {
            const float d = on - m[i];
            en[i] = __builtin_amdgcn_exp2f(fmaf(d * d, C1, C2));
        }
        float l = ((a[0] + a[1]) + (a[2] + a[3])) + ((a[4] + a[5]) + (a[6] + a[7]));
        Z = wave_sum_bcast(l);
        if (renorm) {
            acc2 += __builtin_amdgcn_logf(Z);          // log2(Z), off the chain
            const float r = __builtin_amdgcn_rcpf(Z);  // fold 1/Z into next step
            c9 = 0.9f * r;
            kz = KE;                                   // KE * (r*Z) ~= KE
        } else {
            c9 = 0.9f;
            kz = KE * Z;
        }
#pragma unroll
        for (int i = 0; i < 8; ++i) e[i] = en[i];
    };

    // steps 1..7 (renorm at t=7), then 127 groups of 8 (renorm at t=8g+7)
#pragma unroll
    for (int j = 1; j <= 6; ++j) step(j, false);
    step(7, true);

#pragma unroll 1
    for (int g = 1; g < 128; ++g) {
        const int t0 = g * 8;
#pragma unroll
        for (int j = 0; j < 7; ++j) step(t0 + j, false);
        step(t0 + 7, true);
    }

    // final renorm at t=1023 already folded log2(Z_final) into acc2
    if (lane == 0)
        atomicAdd(out, LN2 * acc2);
}

extern "C" void kernel_launch(void* const* d_in, const int* in_sizes, int n_in,
                              void* d_out, int out_size, void* d_ws, size_t ws_size,
                              hipStream_t stream)
{
    const float* obvs  = (const float*)d_in[0];
    const float* mu    = (const float*)d_in[1];
    const float* ln_pi = (const float*)d_in[2];
    float* out = (float*)d_out;

    (void)hipMemsetAsync(out, 0, sizeof(float), stream);
    hmm_fwd_kernel<<<B_LEN, 64, 0, stream>>>(obvs, mu, ln_pi, out);
}

// Round 4
// 132.442 us; speedup vs baseline: 2.5585x; 1.1190x over previous
//
#include <hip/hip_runtime.h>

#define T_LEN 1024
#define B_LEN 64

// One DPP-add level: x += dpp_move(x, CTRL), out-of-bounds lanes read 0.
template <int CTRL>
__device__ __forceinline__ float dpp_add(float x)
{
    int y = __builtin_amdgcn_update_dpp(0, __builtin_bit_cast(int, x), CTRL, 0xf, 0xf, true);
    return x + __builtin_bit_cast(float, y);
}

// Wave64 sum (row_shr 1/2/4/8 + row_bcast 15/31); total in lane 63, broadcast
// via readlane -> SGPR.
__device__ __forceinline__ float wave_sum_bcast(float x)
{
    x = dpp_add<0x111>(x);  // row_shr:1
    x = dpp_add<0x112>(x);  // row_shr:2
    x = dpp_add<0x114>(x);  // row_shr:4
    x = dpp_add<0x118>(x);  // row_shr:8
    x = dpp_add<0x142>(x);  // row_bcast:15
    x = dpp_add<0x143>(x);  // row_bcast:31
    int z = __builtin_amdgcn_readlane(__builtin_bit_cast(int, x), 63);
    return __builtin_bit_cast(float, z);
}

// Scaled HMM forward; one block = one batch row = one wave; lane owns 8 states.
// alpha' = E o (0.9*alpha + (eps/S)*Z); renorm every 8 steps with 1/Z folded
// into next step's coefficients. Steady-state loop touches NO memory: obs for
// the next 8-step group are prefetched into registers a full group ahead.
__global__ __launch_bounds__(64) void hmm_fwd_kernel(const float* __restrict__ obvs,
                                                     const float* __restrict__ mu,
                                                     const float* __restrict__ ln_pi,
                                                     float* __restrict__ out)
{
    const int b = blockIdx.x;
    const int lane = threadIdx.x;

    __shared__ __align__(16) float s_obs[T_LEN + 8];
    const float* orow = obvs + (size_t)b * T_LEN;
#pragma unroll
    for (int k = 0; k < T_LEN / 64; ++k)
        s_obs[lane + 64 * k] = orow[lane + 64 * k];
    if (lane < 8) s_obs[T_LEN + lane] = 0.0f;   // pad for final group's prefetch
    __syncthreads();

    const float C1    = -0.7213475204444817f;   // -0.5 * log2(e)
    const float C2    = -1.3257480647361593f;   // -0.5 * log2(2*pi)
    const float LOG2E =  1.4426950408889634f;
    const float KE    =  0.1f / 512.0f;         // eps / S
    const float LN2   =  0.6931471805599453f;

    const float4 mua = reinterpret_cast<const float4*>(mu)[2 * lane];
    const float4 mub = reinterpret_cast<const float4*>(mu)[2 * lane + 1];
    const float4 pia = reinterpret_cast<const float4*>(ln_pi)[2 * lane];
    const float4 pib = reinterpret_cast<const float4*>(ln_pi)[2 * lane + 1];
    const float m[8]  = {mua.x, mua.y, mua.z, mua.w, mub.x, mub.y, mub.z, mub.w};
    const float lp[8] = {pia.x, pia.y, pia.z, pia.w, pib.x, pib.y, pib.z, pib.w};
    // emission: exp2(C1*(o-m)^2 + C2) = exp2(C1*o^2 + mp*o + mq)
    float mp[8], mq[8];
#pragma unroll
    for (int i = 0; i < 8; ++i) {
        mp[i] = -2.0f * C1 * m[i];
        mq[i] = fmaf(C1 * m[i], m[i], C2);
    }

    float a[8];
    float Z, c9, kz;
    float acc2 = 0.0f;   // accumulated log2 of normalization scales

    {   // t = 0: alpha_0 = exp2(log2 pi + log2 e0)
        const float o = s_obs[0];
        const float sb = C1 * o * o;
#pragma unroll
        for (int i = 0; i < 8; ++i)
            a[i] = __builtin_amdgcn_exp2f(fmaf(mp[i], o, sb + mq[i]) + lp[i] * LOG2E);
        float l = ((a[0] + a[1]) + (a[2] + a[3])) + ((a[4] + a[5]) + (a[6] + a[7]));
        Z  = wave_sum_bcast(l);
        c9 = 0.9f;
        kz = KE * Z;
    }

    auto stepf = [&](float o, bool renorm) {
        const float sb = C1 * o * o;
        float e[8];
#pragma unroll
        for (int i = 0; i < 8; ++i)
            e[i] = __builtin_amdgcn_exp2f(fmaf(mp[i], o, sb + mq[i]));
#pragma unroll
        for (int i = 0; i < 8; ++i)
            a[i] = e[i] * fmaf(a[i], c9, kz);
        float l = ((a[0] + a[1]) + (a[2] + a[3])) + ((a[4] + a[5]) + (a[6] + a[7]));
        Z = wave_sum_bcast(l);
        if (renorm) {
            acc2 += __builtin_amdgcn_logf(Z);          // log2(Z)
            const float r = __builtin_amdgcn_rcpf(Z);  // fold 1/Z into next step
            c9 = 0.9f * r;
            kz = KE;
        } else {
            c9 = 0.9f;
            kz = KE * Z;
        }
    };

    // prologue: steps 1..7 (scalar LDS obs reads; latency paid once), renorm @7
#pragma unroll
    for (int t = 1; t <= 6; ++t) stepf(s_obs[t], false);
    stepf(s_obs[7], true);

    // preload obs for the first full group (t = 8..15)
    float oc[8];
    {
        const float4 n0 = *reinterpret_cast<const float4*>(&s_obs[8]);
        const float4 n1 = *reinterpret_cast<const float4*>(&s_obs[12]);
        oc[0]=n0.x; oc[1]=n0.y; oc[2]=n0.z; oc[3]=n0.w;
        oc[4]=n1.x; oc[5]=n1.y; oc[6]=n1.z; oc[7]=n1.w;
    }

    // groups g = 1..127: steps 8g..8g+7; prefetch group g+1's obs at group top
#pragma unroll 1
    for (int g = 1; g < 128; ++g) {
        const float4 n0 = *reinterpret_cast<const float4*>(&s_obs[8 * (g + 1)]);
        const float4 n1 = *reinterpret_cast<const float4*>(&s_obs[8 * (g + 1) + 4]);
#pragma unroll
        for (int j = 0; j < 7; ++j) stepf(oc[j], false);
        stepf(oc[7], true);
        oc[0]=n0.x; oc[1]=n0.y; oc[2]=n0.z; oc[3]=n0.w;
        oc[4]=n1.x; oc[5]=n1.y; oc[6]=n1.z; oc[7]=n1.w;
    }

    if (lane == 0)
        atomicAdd(out, LN2 * acc2);
}

extern "C" void kernel_launch(void* const* d_in, const int* in_sizes, int n_in,
                              void* d_out, int out_size, void* d_ws, size_t ws_size,
                              hipStream_t stream)
{
    const float* obvs  = (const float*)d_in[0];
    const float* mu    = (const float*)d_in[1];
    const float* ln_pi = (const float*)d_in[2];
    float* out = (float*)d_out;

    (void)hipMemsetAsync(out, 0, sizeof(float), stream);
    hmm_fwd_kernel<<<B_LEN, 64, 0, stream>>>(obvs, mu, ln_pi, out);
}

// Round 5
// 93.733 us; speedup vs baseline: 3.6151x; 1.4130x over previous
//
#include <hip/hip_runtime.h>

#define T_LEN 1024
#define B_LEN 64

typedef float v2f __attribute__((ext_vector_type(2)));

// One DPP-add level: x += dpp_move(x, CTRL), out-of-bounds lanes read 0.
template <int CTRL>
__device__ __forceinline__ float dpp_add(float x)
{
    int y = __builtin_amdgcn_update_dpp(0, __builtin_bit_cast(int, x), CTRL, 0xf, 0xf, true);
    return x + __builtin_bit_cast(float, y);
}

__device__ __forceinline__ v2f fma2(v2f a, v2f b, v2f c)
{
    return __builtin_elementwise_fma(a, b, c);
}

// Scaled HMM forward; one block = one batch row = one wave; lane owns 8 states
// held as 4 packed-f32 pairs. alpha' = E o (0.9*alpha + (eps/S)*Z).
// The state-uniform Gaussian factor exp2(C1*o^2 + C2-ish) is dropped from E and
// restored at the end via C1 * sum(o^2) (plus C2 via mq). Renorm every 8 steps,
// 1/Z folded into next step's coefficients. Next-step emission prep (pk_fma +
// exp2, Z-independent) is textually interleaved between the DPP reduce levels
// so in-order issue fills the cross-lane latency.
__global__ __launch_bounds__(64) void hmm_fwd_kernel(const float* __restrict__ obvs,
                                                     const float* __restrict__ mu,
                                                     const float* __restrict__ ln_pi,
                                                     float* __restrict__ out)
{
    const int b = blockIdx.x;
    const int lane = threadIdx.x;

    __shared__ __align__(16) float s_obs[T_LEN + 8];
    const float* orow = obvs + (size_t)b * T_LEN;
#pragma unroll
    for (int k = 0; k < T_LEN / 64; ++k)
        s_obs[lane + 64 * k] = orow[lane + 64 * k];
    if (lane < 8) s_obs[T_LEN + lane] = 0.0f;
    __syncthreads();

    const float C1    = -0.7213475204444817f;   // -0.5 * log2(e)
    const float C2    = -1.3257480647361593f;   // -0.5 * log2(2*pi)
    const float LOG2E =  1.4426950408889634f;
    const float KE    =  0.1f / 512.0f;         // eps / S
    const float LN2   =  0.6931471805599453f;

    // per-state constants: reduced emission exponent q~ = mp*o + mq
    v2f mp2[4], mq2[4], lp2[4];
    {
        const float4 mua = reinterpret_cast<const float4*>(mu)[2 * lane];
        const float4 mub = reinterpret_cast<const float4*>(mu)[2 * lane + 1];
        const float4 pia = reinterpret_cast<const float4*>(ln_pi)[2 * lane];
        const float4 pib = reinterpret_cast<const float4*>(ln_pi)[2 * lane + 1];
        const float m[8]  = {mua.x, mua.y, mua.z, mua.w, mub.x, mub.y, mub.z, mub.w};
        const float lp[8] = {pia.x, pia.y, pia.z, pia.w, pib.x, pib.y, pib.z, pib.w};
#pragma unroll
        for (int i = 0; i < 4; ++i) {
            mp2[i] = (v2f){-2.0f * C1 * m[2 * i], -2.0f * C1 * m[2 * i + 1]};
            mq2[i] = (v2f){fmaf(C1 * m[2 * i], m[2 * i], C2),
                           fmaf(C1 * m[2 * i + 1], m[2 * i + 1], C2)};
            lp2[i] = (v2f){lp[2 * i] * LOG2E, lp[2 * i + 1] * LOG2E};
        }
    }

    v2f a2[4], e2[4];          // alpha and current-step emissions
    float Z;
    v2f c9v, kzv;
    float acc2 = 0.0f;         // accumulated log2 of normalization scales
    v2f osq2 = (v2f){0.0f, 0.0f};

    auto stepf = [&](float on, bool renorm) {
        // advance alpha with current emissions (chain: Z -> kzv -> fma -> mul)
#pragma unroll
        for (int i = 0; i < 4; ++i) {
            v2f w = fma2(a2[i], c9v, kzv);
            a2[i] = e2[i] * w;
        }
        v2f s0 = a2[0] + a2[1];
        v2f s1 = a2[2] + a2[3];
        v2f ss = s0 + s1;
        float l = ss[0] + ss[1];
        // next-step emission prep, interleaved with the DPP reduce
        const v2f o2 = (v2f){on, on};
        v2f q0 = fma2(mp2[0], o2, mq2[0]);
        v2f q1 = fma2(mp2[1], o2, mq2[1]);
        l = dpp_add<0x111>(l);                       // row_shr:1
        v2f q2 = fma2(mp2[2], o2, mq2[2]);
        v2f q3 = fma2(mp2[3], o2, mq2[3]);
        l = dpp_add<0x112>(l);                       // row_shr:2
        float e0 = __builtin_amdgcn_exp2f(q0[0]);
        float e1 = __builtin_amdgcn_exp2f(q0[1]);
        l = dpp_add<0x114>(l);                       // row_shr:4
        float e2s = __builtin_amdgcn_exp2f(q1[0]);
        float e3 = __builtin_amdgcn_exp2f(q1[1]);
        l = dpp_add<0x118>(l);                       // row_shr:8
        float e4 = __builtin_amdgcn_exp2f(q2[0]);
        float e5 = __builtin_amdgcn_exp2f(q2[1]);
        l = dpp_add<0x142>(l);                       // row_bcast:15
        float e6 = __builtin_amdgcn_exp2f(q3[0]);
        float e7 = __builtin_amdgcn_exp2f(q3[1]);
        l = dpp_add<0x143>(l);                       // row_bcast:31
        Z = __builtin_bit_cast(float, __builtin_amdgcn_readlane(__builtin_bit_cast(int, l), 63));
        if (renorm) {
            acc2 += __builtin_amdgcn_logf(Z);          // log2(Z)
            const float r = __builtin_amdgcn_rcpf(Z);
            const float c = 0.9f * r;
            c9v = (v2f){c, c};
            kzv = (v2f){KE, KE};
        } else {
            const float kz = KE * Z;
            c9v = (v2f){0.9f, 0.9f};
            kzv = (v2f){kz, kz};
        }
        e2[0] = (v2f){e0, e1}; e2[1] = (v2f){e2s, e3};
        e2[2] = (v2f){e4, e5}; e2[3] = (v2f){e6, e7};
    };

    float oc[8], nx[8];
#pragma unroll
    for (int j = 0; j < 8; ++j) oc[j] = s_obs[j];
#pragma unroll
    for (int j = 0; j < 8; ++j) nx[j] = s_obs[8 + j];

    {   // t = 0: alpha_0 = pi o E~_0
        const v2f o0 = (v2f){oc[0], oc[0]};
#pragma unroll
        for (int i = 0; i < 4; ++i) {
            v2f q = fma2(mp2[i], o0, mq2[i]) + lp2[i];
            a2[i] = (v2f){__builtin_amdgcn_exp2f(q[0]), __builtin_amdgcn_exp2f(q[1])};
        }
        v2f ss = (a2[0] + a2[1]) + (a2[2] + a2[3]);
        float l = ss[0] + ss[1];
        l = dpp_add<0x111>(l); l = dpp_add<0x112>(l); l = dpp_add<0x114>(l);
        l = dpp_add<0x118>(l); l = dpp_add<0x142>(l); l = dpp_add<0x143>(l);
        Z = __builtin_bit_cast(float, __builtin_amdgcn_readlane(__builtin_bit_cast(int, l), 63));
        const float kz = KE * Z;
        c9v = (v2f){0.9f, 0.9f};
        kzv = (v2f){kz, kz};
        const v2f o1 = (v2f){oc[1], oc[1]};      // emissions for t = 1
#pragma unroll
        for (int i = 0; i < 4; ++i) {
            v2f q = fma2(mp2[i], o1, mq2[i]);
            e2[i] = (v2f){__builtin_amdgcn_exp2f(q[0]), __builtin_amdgcn_exp2f(q[1])};
        }
    }
#pragma unroll
    for (int j = 0; j < 8; j += 2)
        osq2 = fma2((v2f){oc[j], oc[j + 1]}, (v2f){oc[j], oc[j + 1]}, osq2);

    // steps t = 1..7 (renorm at 7)
#pragma unroll
    for (int j = 1; j < 7; ++j) stepf(oc[j + 1], false);
    stepf(nx[0], true);
#pragma unroll
    for (int j = 0; j < 8; ++j) oc[j] = nx[j];

    // groups g = 1..127: steps t = 8g..8g+7
#pragma unroll 1
    for (int g = 1; g < 128; ++g) {
        const float4 n0 = *reinterpret_cast<const float4*>(&s_obs[8 * (g + 1)]);
        const float4 n1 = *reinterpret_cast<const float4*>(&s_obs[8 * (g + 1) + 4]);
#pragma unroll
        for (int j = 0; j < 8; j += 2)
            osq2 = fma2((v2f){oc[j], oc[j + 1]}, (v2f){oc[j], oc[j + 1]}, osq2);
#pragma unroll
        for (int j = 0; j < 7; ++j) stepf(oc[j + 1], false);
        stepf(n0.x, true);
        oc[0] = n0.x; oc[1] = n0.y; oc[2] = n0.z; oc[3] = n0.w;
        oc[4] = n1.x; oc[5] = n1.y; oc[6] = n1.z; oc[7] = n1.w;
    }

    if (lane == 0) {
        const float osq = osq2[0] + osq2[1];
        atomicAdd(out, LN2 * (acc2 + C1 * osq));
    }
}

extern "C" void kernel_launch(void* const* d_in, const int* in_sizes, int n_in,
                              void* d_out, int out_size, void* d_ws, size_t ws_size,
                              hipStream_t stream)
{
    const float* obvs  = (const float*)d_in[0];
    const float* mu    = (const float*)d_in[1];
    const float* ln_pi = (const float*)d_in[2];
    float* out = (float*)d_out;

    (void)hipMemsetAsync(out, 0, sizeof(float), stream);
    hmm_fwd_kernel<<<B_LEN, 64, 0, stream>>>(obvs, mu, ln_pi, out);
}